// Round 19
// baseline (14.066 us; speedup 1.0000x reference)
//
#include <hip/hip_runtime.h>

// DLGN_VT v17 — v16 + raw s_barrier (no vmcnt drain) + early V issue:
//   __syncthreads() lowers to s_waitcnt vmcnt(0) lgkmcnt(0); s_barrier — draining all
//   in-flight global loads (12 W at barrier 1, 32 V at barrier 2) even though they are
//   per-thread private. Replace with lgkmcnt(0)-only + raw s_barrier (HK T4 pattern):
//   LDS producer/consumer stays ordered; W/V float across barriers and get fine-grained
//   compiler vmcnt(N) waits at first use. V issued right after barrier 1.
//   Rest identical to v16: 512 blocks x 256 thr, 8 rows/block, pk-FMA phase 1 + 2,
//   DPP combine, readlane g1, Plds deferred reduction.
// No atomics, no memset, no global scratch.

#define BETA 30.0f

typedef float v2f __attribute__((ext_vector_type(2)));

// raw block barrier: drain only LDS ops, leave global loads in flight
__device__ __forceinline__ void lds_sync() {
    asm volatile("s_waitcnt lgkmcnt(0)" ::: "memory");
    __builtin_amdgcn_s_barrier();
    __builtin_amdgcn_sched_barrier(0);   // keep dependent LDS reads below the barrier
}

// quad_perm DPP: full row/bank mask, bound_ctrl=1 -> old-value-independent
__device__ __forceinline__ float qp_xor1(float a) {   // [1,0,3,2] = 0xB1
    return __int_as_float(__builtin_amdgcn_mov_dpp(__float_as_int(a), 0xB1, 0xF, 0xF, true));
}
__device__ __forceinline__ float qp_xor2(float a) {   // [2,3,0,1] = 0x4E
    return __int_as_float(__builtin_amdgcn_mov_dpp(__float_as_int(a), 0x4E, 0xF, 0xF, true));
}

__global__ __launch_bounds__(256, 2) void dlgn_v17_kernel(
    const float* __restrict__ x,
    const float* __restrict__ W1,
    const float* __restrict__ W2,
    const float* __restrict__ W3,
    const float* __restrict__ V,
    float* __restrict__ out)
{
    __shared__ float xlds[8 * 160];   //  5120 B: kc-chunk stride 20
    __shared__ float Gs[8][100];      //  3200 B
    __shared__ float Plds[2560];      // 10240 B: per-thread stride 10

    const int t  = threadIdx.x;
    const int b0 = blockIdx.x * 8;

    // ---- Stage x tile: 1 float4/thread, coalesced; kc-skewed layout ----
    {
        const int r    = t >> 5;
        const int col4 = t & 31;
        const float4 xv = ((const float4*)(x + (size_t)(b0 + r) * 128))[col4];
        const int skc = col4 >> 2, sc = col4 & 3;
        *(float4*)&xlds[r * 160 + skc * 20 + sc * 4] = xv;
    }

    // ---- W chunks -> 48 registers (global, L2-resident; NOT drained at barrier) ----
    const int fl = t >> 3;   // feature-lane 0..31
    const int kc = t & 7;    // k-chunk 0..7
    float4 w1c[4], w2c[4], w3c[4];
    {
        const float4* W1r = (const float4*)(W1 + fl * 128 + kc * 16);
        const float4* W2r = (const float4*)(W2 + fl * 128 + kc * 16);
        const float4* W3r = (const float4*)(W3 + fl * 128 + kc * 16);
#pragma unroll
        for (int c = 0; c < 4; ++c) {
            w1c[c] = W1r[c]; w2c[c] = W2r[c]; w3c[c] = W3r[c];
        }
    }
    lds_sync();   // xlds visible; W/V stay in flight

    // ---- Issue V loads NOW; never force-drained, consumed in phase 2 ----
    const float4* V4 = (const float4*)V;   // f4 idx = i*256 + t
    float4 v[32];
#pragma unroll
    for (int i = 0; i < 32; ++i) v[i] = V4[i * 256 + t];

    // ---- Phase 1: 8 rows x 3 matrices, packed k-eighth partial dots ----
    v2f acc2[3][8];
#pragma unroll
    for (int m = 0; m < 3; ++m)
#pragma unroll
        for (int r = 0; r < 8; ++r) acc2[m][r] = (v2f){0.f, 0.f};

#pragma unroll
    for (int r = 0; r < 8; ++r) {
        float4 xc[4];
#pragma unroll
        for (int c = 0; c < 4; ++c)
            xc[c] = *(const float4*)&xlds[r * 160 + kc * 20 + c * 4];
#pragma unroll
        for (int c = 0; c < 4; ++c) {
            const v2f xlo = (v2f){xc[c].x, xc[c].y};
            const v2f xhi = (v2f){xc[c].z, xc[c].w};
            acc2[0][r] = __builtin_elementwise_fma((v2f){w1c[c].x, w1c[c].y}, xlo, acc2[0][r]);
            acc2[0][r] = __builtin_elementwise_fma((v2f){w1c[c].z, w1c[c].w}, xhi, acc2[0][r]);
            acc2[1][r] = __builtin_elementwise_fma((v2f){w2c[c].x, w2c[c].y}, xlo, acc2[1][r]);
            acc2[1][r] = __builtin_elementwise_fma((v2f){w2c[c].z, w2c[c].w}, xhi, acc2[1][r]);
            acc2[2][r] = __builtin_elementwise_fma((v2f){w3c[c].x, w3c[c].y}, xlo, acc2[2][r]);
            acc2[2][r] = __builtin_elementwise_fma((v2f){w3c[c].z, w3c[c].w}, xhi, acc2[2][r]);
        }
    }

    // ---- Combine k-eighths: horizontal add, DPP xor1/xor2 + shfl xor4; sigmoid -> Gs ----
#pragma unroll
    for (int m = 0; m < 3; ++m) {
        float sel = 0.f;
#pragma unroll
        for (int r = 0; r < 8; ++r) {
            float a = acc2[m][r].x + acc2[m][r].y;
            a += qp_xor1(a);
            a += qp_xor2(a);
            a += __shfl_xor(a, 4);
            if (kc == r) sel = a;      // static select chain
        }
        Gs[kc][32 * m + fl] = 1.0f / (1.0f + __expf(-BETA * sel));
    }
    lds_sync();   // Gs visible; V still in flight

    // ---- Phase 2: thread = (j = t>>3, c2 = t&7); g1 via readlane; packed u ----
    const int j  = t >> 3;   // [0,32)
    const int c2 = t & 7;    // [0,8)

    float p8[8];
#pragma unroll
    for (int b = 0; b < 8; ++b) {
        const float  ga  = Gs[b][t & 31];               // lane l holds g1[b][l&31]
        const float  g2s = Gs[b][32 + j];
        const float4 g3r = *(const float4*)&Gs[b][64 + c2 * 4];

        v2f u2a = (v2f){0.f, 0.f};   // {x,y} accumulator
        v2f u2b = (v2f){0.f, 0.f};   // {z,w} accumulator
#pragma unroll
        for (int i = 0; i < 32; ++i) {
            const float g1i = __int_as_float(
                __builtin_amdgcn_readlane(__float_as_int(ga), i));   // SGPR
            const v2f g1v = (v2f){g1i, g1i};
            u2a = __builtin_elementwise_fma(g1v, (v2f){v[i].x, v[i].y}, u2a);
            u2b = __builtin_elementwise_fma(g1v, (v2f){v[i].z, v[i].w}, u2b);
        }
        float s = u2a.x * g3r.x;
        s = fmaf(u2a.y, g3r.y, s);
        s = fmaf(u2b.x, g3r.z, s);
        s = fmaf(u2b.y, g3r.w, s);
        p8[b] = s * g2s;
    }

    // ---- Deferred reduction: 2 packed b128 writes, raw barrier, one final pass ----
    *(float4*)&Plds[t * 10]     = make_float4(p8[0], p8[1], p8[2], p8[3]);
    *(float4*)&Plds[t * 10 + 4] = make_float4(p8[4], p8[5], p8[6], p8[7]);
    lds_sync();

    {
        const int fb2 = t >> 5;   // b index 0..7
        const int pt  = t & 31;   // partial index
        float s = 0.f;
#pragma unroll
        for (int s8 = 0; s8 < 8; ++s8)
            s += Plds[(pt + s8 * 32) * 10 + fb2];
        s += __shfl_xor(s, 1);
        s += __shfl_xor(s, 2);
        s += __shfl_xor(s, 4);
        s += __shfl_xor(s, 8);
        s += __shfl_xor(s, 16);
        if (pt == 0) out[b0 + fb2] = s;
    }
}

extern "C" void kernel_launch(void* const* d_in, const int* in_sizes, int n_in,
                              void* d_out, int out_size, void* d_ws, size_t ws_size,
                              hipStream_t stream) {
    const float* x  = (const float*)d_in[0];
    const float* W1 = (const float*)d_in[1];
    const float* W2 = (const float*)d_in[2];
    const float* W3 = (const float*)d_in[3];
    const float* V  = (const float*)d_in[4];
    float* out = (float*)d_out;

    dlgn_v17_kernel<<<dim3(512), dim3(256), 0, stream>>>(x, W1, W2, W3, V, out);
}

// Round 20
// 12.431 us; speedup vs baseline: 1.1315x; 1.1315x over previous
//
#include <hip/hip_runtime.h>

// DLGN_VT v18 — v16 base, readlane->LDS-broadcast g1, all-DPP combine:
//   512 blocks x 256 thr, 8 rows/block, launch_bounds(256,2). LDS 18.6 KB.
//   Phase 1 (= v16): thread (fl=t>>3, kc=t&7) holds W1/2/3 chunks in 48 regs;
//     x kc-skewed in LDS; 8 rows x 24 pk-FMA; combine k-eighths now PURE VALU:
//     DPP quad_perm xor1/xor2 + DPP ROW_HALF_MIRROR (opposite-quad sum) -> sigmoid -> Gs.
//   V loads issued after phase-1 FMA.
//   Phase 2: per b: g1 row via 8 uniform-broadcast ds_read_b128 into VGPRs (v6
//     delivery — removes 256 v_readlane + SGPR hazards); 64 pk-FMA i-first; g2/g3 reads.
//   Reduce: p8 -> Plds (stride 10), barrier, 8 reads + DPP xor1/2/4/8 + shfl xor16.
// No atomics, no memset, no global scratch.

#define BETA 30.0f

typedef float v2f __attribute__((ext_vector_type(2)));

__device__ __forceinline__ float f4c(const float4 v, int c) {
    return c == 0 ? v.x : (c == 1 ? v.y : (c == 2 ? v.z : v.w));
}

// DPP helpers: full row/bank mask, bound_ctrl=1 -> old-value-independent
__device__ __forceinline__ float qp_xor1(float a) {   // quad_perm [1,0,3,2] = 0xB1
    return __int_as_float(__builtin_amdgcn_mov_dpp(__float_as_int(a), 0xB1, 0xF, 0xF, true));
}
__device__ __forceinline__ float qp_xor2(float a) {   // quad_perm [2,3,0,1] = 0x4E
    return __int_as_float(__builtin_amdgcn_mov_dpp(__float_as_int(a), 0x4E, 0xF, 0xF, true));
}
__device__ __forceinline__ float dpp_half_mirror(float a) {   // lane i <-> 7-i within 8
    return __int_as_float(__builtin_amdgcn_mov_dpp(__float_as_int(a), 0x141, 0xF, 0xF, true));
}
__device__ __forceinline__ float dpp_row_mirror(float a) {    // lane i <-> 15-i within 16
    return __int_as_float(__builtin_amdgcn_mov_dpp(__float_as_int(a), 0x140, 0xF, 0xF, true));
}

__global__ __launch_bounds__(256, 2) void dlgn_v18_kernel(
    const float* __restrict__ x,
    const float* __restrict__ W1,
    const float* __restrict__ W2,
    const float* __restrict__ W3,
    const float* __restrict__ V,
    float* __restrict__ out)
{
    __shared__ float xlds[8 * 160];   //  5120 B: kc-chunk stride 20
    __shared__ float Gs[8][100];      //  3200 B
    __shared__ float Plds[2560];      // 10240 B: per-thread stride 10

    const int t  = threadIdx.x;
    const int b0 = blockIdx.x * 8;

    // ---- Stage x tile: 1 float4/thread, coalesced; kc-skewed layout ----
    {
        const int r    = t >> 5;
        const int col4 = t & 31;
        const float4 xv = ((const float4*)(x + (size_t)(b0 + r) * 128))[col4];
        const int skc = col4 >> 2, sc = col4 & 3;
        *(float4*)&xlds[r * 160 + skc * 20 + sc * 4] = xv;
    }

    // ---- W chunks -> 48 registers (global, L2-resident) ----
    const int fl = t >> 3;   // feature-lane 0..31
    const int kc = t & 7;    // k-chunk 0..7
    float4 w1c[4], w2c[4], w3c[4];
    {
        const float4* W1r = (const float4*)(W1 + fl * 128 + kc * 16);
        const float4* W2r = (const float4*)(W2 + fl * 128 + kc * 16);
        const float4* W3r = (const float4*)(W3 + fl * 128 + kc * 16);
#pragma unroll
        for (int c = 0; c < 4; ++c) {
            w1c[c] = W1r[c]; w2c[c] = W2r[c]; w3c[c] = W3r[c];
        }
    }
    __syncthreads();   // xlds ready

    // ---- Phase 1: 8 rows x 3 matrices, packed k-eighth partial dots ----
    v2f acc2[3][8];
#pragma unroll
    for (int m = 0; m < 3; ++m)
#pragma unroll
        for (int r = 0; r < 8; ++r) acc2[m][r] = (v2f){0.f, 0.f};

#pragma unroll
    for (int r = 0; r < 8; ++r) {
        float4 xc[4];
#pragma unroll
        for (int c = 0; c < 4; ++c)
            xc[c] = *(const float4*)&xlds[r * 160 + kc * 20 + c * 4];
#pragma unroll
        for (int c = 0; c < 4; ++c) {
            const v2f xlo = (v2f){xc[c].x, xc[c].y};
            const v2f xhi = (v2f){xc[c].z, xc[c].w};
            acc2[0][r] = __builtin_elementwise_fma((v2f){w1c[c].x, w1c[c].y}, xlo, acc2[0][r]);
            acc2[0][r] = __builtin_elementwise_fma((v2f){w1c[c].z, w1c[c].w}, xhi, acc2[0][r]);
            acc2[1][r] = __builtin_elementwise_fma((v2f){w2c[c].x, w2c[c].y}, xlo, acc2[1][r]);
            acc2[1][r] = __builtin_elementwise_fma((v2f){w2c[c].z, w2c[c].w}, xhi, acc2[1][r]);
            acc2[2][r] = __builtin_elementwise_fma((v2f){w3c[c].x, w3c[c].y}, xlo, acc2[2][r]);
            acc2[2][r] = __builtin_elementwise_fma((v2f){w3c[c].z, w3c[c].w}, xhi, acc2[2][r]);
        }
    }

    // ---- Issue V loads now (W regs dead); complete under combine + barrier ----
    const float4* V4 = (const float4*)V;   // f4 idx = i*256 + t
    float4 v[32];
#pragma unroll
    for (int i = 0; i < 32; ++i) v[i] = V4[i * 256 + t];

    // ---- Combine k-eighths: PURE VALU (DPP xor1, xor2, half-mirror); sigmoid -> Gs ----
#pragma unroll
    for (int m = 0; m < 3; ++m) {
        float sel = 0.f;
#pragma unroll
        for (int r = 0; r < 8; ++r) {
            float a = acc2[m][r].x + acc2[m][r].y;
            a += qp_xor1(a);
            a += qp_xor2(a);          // each quad now holds its quad-sum (uniform)
            a += dpp_half_mirror(a);  // adds the opposite quad's sum -> full 8-sum
            if (kc == r) sel = a;     // static select chain
        }
        Gs[kc][32 * m + fl] = 1.0f / (1.0f + __expf(-BETA * sel));
    }
    __syncthreads();

    // ---- Phase 2: thread = (j = t>>3, c2 = t&7); g1 via LDS broadcast into VGPRs ----
    const int j  = t >> 3;   // [0,32)
    const int c2 = t & 7;    // [0,8)

    float p8[8];
#pragma unroll
    for (int b = 0; b < 8; ++b) {
        const float4* Gr = (const float4*)&Gs[b][0];
        float4 g1r[8];
#pragma unroll
        for (int c = 0; c < 8; ++c) g1r[c] = Gr[c];    // uniform broadcast, conflict-free
        const float  g2s = Gs[b][32 + j];
        const float4 g3r = *(const float4*)&Gs[b][64 + c2 * 4];

        v2f u2a = (v2f){0.f, 0.f};   // {x,y} accumulator
        v2f u2b = (v2f){0.f, 0.f};   // {z,w} accumulator
#pragma unroll
        for (int i = 0; i < 32; ++i) {
            const float g1i = f4c(g1r[i >> 2], i & 3);   // static reg pick
            const v2f g1v = (v2f){g1i, g1i};
            u2a = __builtin_elementwise_fma(g1v, (v2f){v[i].x, v[i].y}, u2a);
            u2b = __builtin_elementwise_fma(g1v, (v2f){v[i].z, v[i].w}, u2b);
        }
        float s = u2a.x * g3r.x;
        s = fmaf(u2a.y, g3r.y, s);
        s = fmaf(u2b.x, g3r.z, s);
        s = fmaf(u2b.y, g3r.w, s);
        p8[b] = s * g2s;
    }

    // ---- Deferred reduction: 2 packed b128 writes, barrier, DPP-heavy final pass ----
    *(float4*)&Plds[t * 10]     = make_float4(p8[0], p8[1], p8[2], p8[3]);
    *(float4*)&Plds[t * 10 + 4] = make_float4(p8[4], p8[5], p8[6], p8[7]);
    __syncthreads();

    {
        const int fb2 = t >> 5;   // b index 0..7
        const int pt  = t & 31;   // partial index
        float s = 0.f;
#pragma unroll
        for (int s8 = 0; s8 < 8; ++s8)
            s += Plds[(pt + s8 * 32) * 10 + fb2];
        s += qp_xor1(s);
        s += qp_xor2(s);
        s += dpp_half_mirror(s);   // 8-sum
        s += dpp_row_mirror(s);    // 16-sum
        s += __shfl_xor(s, 16);    // 32-sum (crosses DPP row boundary)
        if (pt == 0) out[b0 + fb2] = s;
    }
}

extern "C" void kernel_launch(void* const* d_in, const int* in_sizes, int n_in,
                              void* d_out, int out_size, void* d_ws, size_t ws_size,
                              hipStream_t stream) {
    const float* x  = (const float*)d_in[0];
    const float* W1 = (const float*)d_in[1];
    const float* W2 = (const float*)d_in[2];
    const float* W3 = (const float*)d_in[3];
    const float* V  = (const float*)d_in[4];
    float* out = (float*)d_out;

    dlgn_v18_kernel<<<dim3(512), dim3(256), 0, stream>>>(x, W1, W2, W3, V, out);
}